// Round 1
// baseline (3509.296 us; speedup 1.0000x reference)
//
#include <hip/hip_runtime.h>
#include <math.h>

#define BB 16
#define CH 64
#define SS 128
#define HH 137
#define NP 18769   // 137*137
#define MM 16
#define KK 32      // 16 top + 16 bottom kx modes
#define NL 4

__device__ __forceinline__ float gelu_f(float x) {
    return 0.5f * x * (1.0f + erff(x * 0.70710678118654752440f));
}

// ---- twiddle init (recomputed every launch; double precision) ----
// Wy[y*16+ky] = exp(-2*pi*i*y*ky/137)   (137*16)
// Wx[x*32+ki] = exp(-2*pi*i*x*K/137), K = ki<16 ? ki : 105+ki   (137*32)
__global__ void k_init_twiddles(float2* __restrict__ Wy, float2* __restrict__ Wx) {
    int t = blockIdx.x * 256 + threadIdx.x;
    const double PI2 = 6.283185307179586476925286766559;
    if (t < HH * MM) {
        int y = t >> 4, k = t & 15;
        int m = (y * k) % HH;
        double ang = -PI2 * (double)m / (double)HH;
        Wy[t] = make_float2((float)cos(ang), (float)sin(ang));
    } else if (t < HH * MM + HH * KK) {
        int u = t - HH * MM;
        int x = u >> 5, ki = u & 31;
        int K = (ki < 16) ? ki : (105 + ki);
        int m = (x * K) % HH;
        double ang = -PI2 * (double)m / (double)HH;
        Wx[u] = make_float2((float)cos(ang), (float)sin(ang));
    }
}

// ---- projection (concat grids + 7->64 conv1x1) into padded 137x137, pad=0 ----
__global__ void k_proj(const float* __restrict__ x, const float* __restrict__ pw,
                       const float* __restrict__ pb, float* __restrict__ X0) {
    int t = blockIdx.x * 256 + threadIdx.x;       // B*CH*NP threads exactly
    int b = t / (CH * NP);
    int r = t - b * (CH * NP);
    int d = r / NP;
    int s = r - d * NP;
    int X = s / HH, Y = s - X * HH;
    float v = 0.f;
    if (X < SS && Y < SS) {
        v = pb[d];
        #pragma unroll
        for (int c = 0; c < 5; c++)
            v += x[((b * 5 + c) * SS + X) * SS + Y] * pw[c * CH + d];
        v += ((float)X * (1.0f / 127.0f)) * pw[5 * CH + d];
        v += ((float)Y * (1.0f / 127.0f)) * pw[6 * CH + d];
    }
    X0[t] = v;
}

// ---- forward DFT along y: T[bi][x][ky] = sum_y X0[bi][x][y] * Wy[y][ky] ----
__global__ void k_dfty(const float* __restrict__ X0, const float2* __restrict__ Wy,
                       float2* __restrict__ T) {
    __shared__ float rows[16 * HH];
    __shared__ float2 wy[HH * MM];
    int bi = blockIdx.y;
    int xc = blockIdx.x;     // 0..8, chunk of 16 x-rows
    for (int idx = threadIdx.x; idx < HH * MM; idx += 256) wy[idx] = Wy[idx];
    for (int idx = threadIdx.x; idx < 16 * HH; idx += 256) {
        int xl = idx / HH, y = idx - xl * HH;
        int gx = xc * 16 + xl;
        rows[idx] = (gx < HH) ? X0[bi * NP + gx * HH + y] : 0.f;
    }
    __syncthreads();
    int ky = threadIdx.x & 15;
    int xl = threadIdx.x >> 4;
    int gx = xc * 16 + xl;
    if (gx >= HH) return;
    float tr = 0.f, ti = 0.f;
    const float* row = &rows[xl * HH];
    for (int y = 0; y < HH; y++) {
        float v = row[y];
        float2 w = wy[y * MM + ky];
        tr += v * w.x;
        ti += v * w.y;
    }
    T[(bi * HH + gx) * MM + ky] = make_float2(tr, ti);
}

// ---- forward DFT along x (32 kept modes): F[bi][kx][ky] ----
__global__ void k_dftx(const float2* __restrict__ T, const float2* __restrict__ Wx,
                       float2* __restrict__ F) {
    int t = blockIdx.x * 256 + threadIdx.x;   // B*CH*KK*MM exactly
    int ky = t & 15;
    int kx = (t >> 4) & 31;
    int bi = t >> 9;
    float fr = 0.f, fi = 0.f;
    for (int x = 0; x < HH; x++) {
        float2 tv = T[(bi * HH + x) * MM + ky];
        float2 w = Wx[x * KK + kx];
        fr += tv.x * w.x - tv.y * w.y;
        fi += tv.x * w.y + tv.y * w.x;
    }
    F[t] = make_float2(fr, fi);
}

// ---- spectral multiply: G[b][o][kx][ky] = sum_i F[b][i][kx][ky] * w[i][o][kx][ky] ----
__global__ void k_specmul(const float2* __restrict__ F, const float* __restrict__ sw1,
                          const float* __restrict__ sw2, int layer, float2* __restrict__ G) {
    int t = blockIdx.x * 256 + threadIdx.x;
    int ky = t & 15;
    int kx = (t >> 4) & 31;
    int o  = (t >> 9) & 63;
    int b  = t >> 15;
    const float* wb0;
    int kk;
    if (kx < 16) { wb0 = sw1; kk = kx; } else { wb0 = sw2; kk = kx - 16; }
    // sw layout: [layer][reim][i][o][kx][ky], strides: layer 2097152, reim 1048576, i 16384, o 256, kx 16
    wb0 += layer * 2097152 + o * 256 + kk * 16 + ky;
    float gr = 0.f, gi = 0.f;
    for (int i = 0; i < CH; i++) {
        float2 f = F[((b * CH + i) * KK + kx) * MM + ky];
        float wr = wb0[i * 16384];
        float wi = wb0[i * 16384 + 1048576];
        gr += f.x * wr - f.y * wi;
        gi += f.x * wi + f.y * wr;
    }
    G[t] = make_float2(gr, gi);
}

// ---- inverse DFT along x: Hh[bo][x][ky] = (wk/NP) * sum_kx G * conj(Wx) ----
__global__ void k_invx(const float2* __restrict__ G, const float2* __restrict__ Wx,
                       float2* __restrict__ Hh) {
    int t = blockIdx.x * 256 + threadIdx.x;  // B*CH*HH*MM exactly
    int ky = t & 15;
    int r = t >> 4;
    int x = r % HH;
    int bo = r / HH;
    float hr = 0.f, hi = 0.f;
    #pragma unroll 8
    for (int kx = 0; kx < KK; kx++) {
        float2 g = G[(bo * KK + kx) * MM + ky];
        float2 w = Wx[x * KK + kx];
        hr += g.x * w.x + g.y * w.y;
        hi += g.y * w.x - g.x * w.y;
    }
    float sc = (ky == 0 ? 1.0f : 2.0f) / 18769.0f;
    Hh[(bo * HH + x) * MM + ky] = make_float2(hr * sc, hi * sc);
}

// ---- inverse along y: X1[bo][x][y] = sum_ky (hr*Wyr + hi*Wyi) ----
__global__ void k_invy(const float2* __restrict__ Hh, const float2* __restrict__ Wy,
                       float* __restrict__ X1) {
    int t = blockIdx.x * 256 + threadIdx.x;   // B*CH*NP exactly
    int y = t % HH;
    int r = t / HH;
    int x = r % HH;
    int bo = r / HH;
    float acc = 0.f;
    #pragma unroll
    for (int ky = 0; ky < MM; ky++) {
        float2 h = Hh[(bo * HH + x) * MM + ky];
        float2 w = Wy[y * MM + ky];
        acc += h.x * w.x + h.y * w.y;
    }
    X1[t] = acc;
}

// ---- fused layer tail: x = gelu( mlp2(gelu(mlp1(x1))) + ww(x) ), in-place on X0 ----
__global__ void __launch_bounds__(256) k_tail(float* __restrict__ X0, const float* __restrict__ X1,
    const float* __restrict__ w1, const float* __restrict__ b1,
    const float* __restrict__ w2, const float* __restrict__ b2,
    const float* __restrict__ wwp, const float* __restrict__ wbp, int layer) {
    __shared__ float vx[CH * 64];
    __shared__ float v1[CH * 64];
    __shared__ float tb[CH * 64];
    int b = blockIdx.y;
    int s0 = blockIdx.x * 64;
    for (int idx = threadIdx.x; idx < CH * 64; idx += 256) {
        int c = idx >> 6, pp = idx & 63;
        int s = s0 + pp;
        float a = 0.f, bbv = 0.f;
        if (s < NP) {
            a   = X0[(b * CH + c) * NP + s];
            bbv = X1[(b * CH + c) * NP + s];
        }
        vx[idx] = a;
        v1[idx] = bbv;
    }
    __syncthreads();
    int p = threadIdx.x & 63;
    int og = __builtin_amdgcn_readfirstlane(threadIdx.x >> 6);  // wave-uniform -> scalar weight loads
    int s = s0 + p;
    const float* W1 = w1  + layer * CH * CH + og * 16 * CH;
    const float* W2 = w2  + layer * CH * CH + og * 16 * CH;
    const float* WW = wwp + layer * CH * CH + og * 16 * CH;
    float acc[16];
    #pragma unroll
    for (int oo = 0; oo < 16; oo++) acc[oo] = b1[layer * CH + og * 16 + oo];
    for (int i = 0; i < CH; i++) {
        float v = v1[i * 64 + p];
        #pragma unroll
        for (int oo = 0; oo < 16; oo++)
            acc[oo] += W1[oo * CH + i] * v;
    }
    #pragma unroll
    for (int oo = 0; oo < 16; oo++)
        tb[(og * 16 + oo) * 64 + p] = gelu_f(acc[oo]);
    __syncthreads();
    #pragma unroll
    for (int oo = 0; oo < 16; oo++)
        acc[oo] = b2[layer * CH + og * 16 + oo] + wbp[layer * CH + og * 16 + oo];
    for (int j = 0; j < CH; j++) {
        float v = tb[j * 64 + p];
        #pragma unroll
        for (int oo = 0; oo < 16; oo++)
            acc[oo] += W2[oo * CH + j] * v;
    }
    for (int i = 0; i < CH; i++) {
        float v = vx[i * 64 + p];
        #pragma unroll
        for (int oo = 0; oo < 16; oo++)
            acc[oo] += WW[oo * CH + i] * v;
    }
    if (s < NP) {
        #pragma unroll
        for (int oo = 0; oo < 16; oo++)
            X0[(b * CH + og * 16 + oo) * NP + s] = gelu_f(acc[oo]);
    }
}

// ---- final head: crop + q1(64->256) + gelu + q2(256->1) ----
__global__ void __launch_bounds__(256) k_final(const float* __restrict__ X0,
    const float* __restrict__ q1w, const float* __restrict__ q1b,
    const float* __restrict__ q2w, const float* __restrict__ q2b,
    float* __restrict__ out) {
    __shared__ float v[CH * 64];
    __shared__ float part[4][64];
    int ys = blockIdx.x;   // 0..1
    int X  = blockIdx.y;   // 0..127
    int b  = blockIdx.z;   // 0..15
    int y0 = ys * 64;
    for (int idx = threadIdx.x; idx < CH * 64; idx += 256) {
        int c = idx >> 6, pp = idx & 63;
        v[idx] = X0[(b * CH + c) * NP + X * HH + (y0 + pp)];
    }
    __syncthreads();
    int p = threadIdx.x & 63;
    int og = __builtin_amdgcn_readfirstlane(threadIdx.x >> 6);
    float qacc = 0.f;
    for (int chunk = 0; chunk < 4; chunk++) {
        int jbase = og * 64 + chunk * 16;
        float acc[16];
        #pragma unroll
        for (int tt = 0; tt < 16; tt++) acc[tt] = q1b[jbase + tt];
        for (int i = 0; i < CH; i++) {
            float vv = v[i * 64 + p];
            #pragma unroll
            for (int tt = 0; tt < 16; tt++)
                acc[tt] += q1w[(jbase + tt) * CH + i] * vv;
        }
        #pragma unroll
        for (int tt = 0; tt < 16; tt++)
            qacc += q2w[jbase + tt] * gelu_f(acc[tt]);
    }
    part[og][p] = qacc;
    __syncthreads();
    if (og == 0) {
        float r = part[0][p] + part[1][p] + part[2][p] + part[3][p] + q2b[0];
        out[(b * SS + X) * SS + (y0 + p)] = r;
    }
}

extern "C" void kernel_launch(void* const* d_in, const int* in_sizes, int n_in,
                              void* d_out, int out_size, void* d_ws, size_t ws_size,
                              hipStream_t stream) {
    const float* x   = (const float*)d_in[0];
    const float* p_w = (const float*)d_in[1];
    const float* p_b = (const float*)d_in[2];
    const float* sw1 = (const float*)d_in[3];
    const float* sw2 = (const float*)d_in[4];
    const float* m1w = (const float*)d_in[5];
    const float* m1b = (const float*)d_in[6];
    const float* m2w = (const float*)d_in[7];
    const float* m2b = (const float*)d_in[8];
    const float* wwp = (const float*)d_in[9];
    const float* wbp = (const float*)d_in[10];
    const float* q1w = (const float*)d_in[11];
    const float* q1b = (const float*)d_in[12];
    const float* q2w = (const float*)d_in[13];
    const float* q2b = (const float*)d_in[14];

    float* ws = (float*)d_ws;
    float*  X0 = ws;                                    // B*CH*NP
    float*  X1 = X0 + (size_t)BB * CH * NP;             // B*CH*NP
    float2* T  = (float2*)(X1 + (size_t)BB * CH * NP);  // B*CH*HH*MM complex
    float2* F  = T + (size_t)BB * CH * HH * MM;         // B*CH*KK*MM complex
    float2* G  = F + (size_t)BB * CH * KK * MM;
    float2* Wy = G + (size_t)BB * CH * KK * MM;         // HH*MM
    float2* Wx = Wy + HH * MM;                          // HH*KK

    k_init_twiddles<<<26, 256, 0, stream>>>(Wy, Wx);
    k_proj<<<(BB * CH * NP) / 256, 256, 0, stream>>>(x, p_w, p_b, X0);
    for (int layer = 0; layer < NL; layer++) {
        k_dfty<<<dim3(9, BB * CH), 256, 0, stream>>>(X0, Wy, T);
        k_dftx<<<(BB * CH * KK * MM) / 256, 256, 0, stream>>>(T, Wx, F);
        k_specmul<<<(BB * CH * KK * MM) / 256, 256, 0, stream>>>(F, sw1, sw2, layer, G);
        k_invx<<<(BB * CH * HH * MM) / 256, 256, 0, stream>>>(G, Wx, T);
        k_invy<<<(BB * CH * NP) / 256, 256, 0, stream>>>(T, Wy, X1);
        k_tail<<<dim3(294, BB), 256, 0, stream>>>(X0, X1, m1w, m1b, m2w, m2b, wwp, wbp, layer);
    }
    k_final<<<dim3(2, SS, BB), 256, 0, stream>>>(X0, q1w, q1b, q2w, q2b, (float*)d_out);
}

// Round 2
// 3193.628 us; speedup vs baseline: 1.0988x; 1.0988x over previous
//
#include <hip/hip_runtime.h>
#include <math.h>

#define BB 16
#define CH 64
#define SS 128
#define HH 137
#define NP 18769   // 137*137
#define MM 16
#define KK 32      // 16 top + 16 bottom kx modes
#define NL 4
#define PT 192     // pixel tile for tail GEMMs

__device__ __forceinline__ float gelu_f(float x) {
    return 0.5f * x * (1.0f + erff(x * 0.70710678118654752440f));
}

// ---- twiddle init ----
__global__ void k_init_twiddles(float2* __restrict__ Wy, float2* __restrict__ Wx) {
    int t = blockIdx.x * 256 + threadIdx.x;
    const double PI2 = 6.283185307179586476925286766559;
    if (t < HH * MM) {
        int y = t >> 4, k = t & 15;
        int m = (y * k) % HH;
        double ang = -PI2 * (double)m / (double)HH;
        Wy[t] = make_float2((float)cos(ang), (float)sin(ang));
    } else if (t < HH * MM + HH * KK) {
        int u = t - HH * MM;
        int x = u >> 5, ki = u & 31;
        int K = (ki < 16) ? ki : (105 + ki);
        int m = (x * K) % HH;
        double ang = -PI2 * (double)m / (double)HH;
        Wx[u] = make_float2((float)cos(ang), (float)sin(ang));
    }
}

// ---- projection ----
__global__ void k_proj(const float* __restrict__ x, const float* __restrict__ pw,
                       const float* __restrict__ pb, float* __restrict__ X0) {
    int t = blockIdx.x * 256 + threadIdx.x;
    int b = t / (CH * NP);
    int r = t - b * (CH * NP);
    int d = r / NP;
    int s = r - d * NP;
    int X = s / HH, Y = s - X * HH;
    float v = 0.f;
    if (X < SS && Y < SS) {
        v = pb[d];
        #pragma unroll
        for (int c = 0; c < 5; c++)
            v += x[((b * 5 + c) * SS + X) * SS + Y] * pw[c * CH + d];
        v += ((float)X * (1.0f / 127.0f)) * pw[5 * CH + d];
        v += ((float)Y * (1.0f / 127.0f)) * pw[6 * CH + d];
    }
    X0[t] = v;
}

// ---- forward DFT along y (LDS-transposed K-chunks, Wy broadcast) ----
// T[row][ky] (float2), row = bi*137 + x, rows = 140288 = 548*256
__global__ void __launch_bounds__(256) k_dfty2(const float* __restrict__ X0,
                                               const float2* __restrict__ Wy,
                                               float2* __restrict__ T) {
    __shared__ float sXT[32 * 258];    // [yy][r] chunk, stride 258 -> 2-way on write
    __shared__ float4 sWy[HH * 8];     // [y][8] float4 pairs of (wr,wi)
    int tid = threadIdx.x;
    int r0 = blockIdx.x * 256;
    for (int idx = tid; idx < HH * 8; idx += 256)
        sWy[idx] = ((const float4*)Wy)[idx];
    float acc[32];
    #pragma unroll
    for (int q = 0; q < 32; q++) acc[q] = 0.f;
    for (int yc = 0; yc < 5; yc++) {
        int y0 = yc * 32;
        int ylen = (y0 + 32 <= HH) ? 32 : (HH - y0);
        __syncthreads();
        for (int idx = tid; idx < 256 * 32; idx += 256) {
            int r = idx >> 5, yy = idx & 31;
            int y = y0 + yy;
            sXT[yy * 258 + r] = (y < HH) ? X0[(size_t)(r0 + r) * HH + y] : 0.f;
        }
        __syncthreads();
        for (int yy = 0; yy < ylen; yy++) {
            float v = sXT[yy * 258 + tid];
            int y = y0 + yy;
            #pragma unroll
            for (int q = 0; q < 8; q++) {
                float4 w = sWy[y * 8 + q];
                acc[4 * q + 0] += v * w.x;
                acc[4 * q + 1] += v * w.y;
                acc[4 * q + 2] += v * w.z;
                acc[4 * q + 3] += v * w.w;
            }
        }
    }
    float4* To = (float4*)(T + (size_t)(r0 + tid) * MM);
    #pragma unroll
    for (int q = 0; q < 8; q++)
        To[q] = make_float4(acc[4 * q], acc[4 * q + 1], acc[4 * q + 2], acc[4 * q + 3]);
}

// ---- forward DFT along x (unchanged) ----
__global__ void k_dftx(const float2* __restrict__ T, const float2* __restrict__ Wx,
                       float2* __restrict__ F) {
    int t = blockIdx.x * 256 + threadIdx.x;
    int ky = t & 15;
    int kx = (t >> 4) & 31;
    int bi = t >> 9;
    float fr = 0.f, fi = 0.f;
    for (int x = 0; x < HH; x++) {
        float2 tv = T[(bi * HH + x) * MM + ky];
        float2 w = Wx[x * KK + kx];
        fr += tv.x * w.x - tv.y * w.y;
        fi += tv.x * w.y + tv.y * w.x;
    }
    F[t] = make_float2(fr, fi);
}

// ---- spectral multiply (unchanged) ----
__global__ void k_specmul(const float2* __restrict__ F, const float* __restrict__ sw1,
                          const float* __restrict__ sw2, int layer, float2* __restrict__ G) {
    int t = blockIdx.x * 256 + threadIdx.x;
    int ky = t & 15;
    int kx = (t >> 4) & 31;
    int o  = (t >> 9) & 63;
    int b  = t >> 15;
    const float* wb0;
    int kk;
    if (kx < 16) { wb0 = sw1; kk = kx; } else { wb0 = sw2; kk = kx - 16; }
    wb0 += layer * 2097152 + o * 256 + kk * 16 + ky;
    float gr = 0.f, gi = 0.f;
    for (int i = 0; i < CH; i++) {
        float2 f = F[((b * CH + i) * KK + kx) * MM + ky];
        float wr = wb0[i * 16384];
        float wi = wb0[i * 16384 + 1048576];
        gr += f.x * wr - f.y * wi;
        gi += f.x * wi + f.y * wr;
    }
    G[t] = make_float2(gr, gi);
}

// ---- inverse DFT along x (unchanged; writes Hh) ----
__global__ void k_invx(const float2* __restrict__ G, const float2* __restrict__ Wx,
                       float2* __restrict__ Hh) {
    int t = blockIdx.x * 256 + threadIdx.x;
    int ky = t & 15;
    int r = t >> 4;
    int x = r % HH;
    int bo = r / HH;
    float hr = 0.f, hi = 0.f;
    #pragma unroll 8
    for (int kx = 0; kx < KK; kx++) {
        float2 g = G[(bo * KK + kx) * MM + ky];
        float2 w = Wx[x * KK + kx];
        hr += g.x * w.x + g.y * w.y;
        hi += g.y * w.x - g.x * w.y;
    }
    float sc = (ky == 0 ? 1.0f : 2.0f) / 18769.0f;
    Hh[(bo * HH + x) * MM + ky] = make_float2(hr * sc, hi * sc);
}

// ---- spectral mlp1: Hh2[b][p][·] = sum_o m1[p][o] * Hh[b][o][·]  (real GEMM on 4384 real cols) ----
__global__ void __launch_bounds__(128) k_mlp1s(const float* __restrict__ Hh,
                                               const float* __restrict__ m1w, int layer,
                                               float* __restrict__ Hh2) {
    __shared__ float sH[CH * 128];   // [o][j] 32KB
    __shared__ float sM[CH * 72];    // [o][p] 18KB
    int tid = threadIdx.x;
    int b = blockIdx.y;
    int c0 = blockIdx.x * 128;       // real-float col offset, cols total 4384
    for (int idx = tid; idx < CH * 128; idx += 128) {
        int o = idx >> 7, j = idx & 127;
        int cc = c0 + j;
        sH[idx] = (cc < 4384) ? Hh[(size_t)(b * CH + o) * 4384 + cc] : 0.f;
    }
    for (int idx = tid; idx < 4096; idx += 128) {
        int p = idx >> 6, o = idx & 63;
        sM[o * 72 + p] = m1w[layer * 4096 + p * 64 + o];
    }
    __syncthreads();
    int pgrp = tid & 7, cg = tid >> 3;
    int p0 = pgrp * 8, cr0 = cg * 8;
    float acc[8][8];
    #pragma unroll
    for (int a = 0; a < 8; a++)
        #pragma unroll
        for (int c = 0; c < 8; c++) acc[a][c] = 0.f;
    for (int o = 0; o < CH; o++) {
        float4 wA = *(const float4*)&sM[o * 72 + p0];
        float4 wB = *(const float4*)&sM[o * 72 + p0 + 4];
        float4 vA = *(const float4*)&sH[o * 128 + cr0];
        float4 vB = *(const float4*)&sH[o * 128 + cr0 + 4];
        float wv[8] = {wA.x, wA.y, wA.z, wA.w, wB.x, wB.y, wB.z, wB.w};
        float vv[8] = {vA.x, vA.y, vA.z, vA.w, vB.x, vB.y, vB.z, vB.w};
        #pragma unroll
        for (int a = 0; a < 8; a++)
            #pragma unroll
            for (int c = 0; c < 8; c++) acc[a][c] += wv[a] * vv[c];
    }
    #pragma unroll
    for (int a = 0; a < 8; a++) {
        size_t rowb = (size_t)(b * CH + p0 + a) * 4384;
        #pragma unroll
        for (int c = 0; c < 8; c++) {
            int cc = c0 + cr0 + c;
            if (cc < 4384) Hh2[rowb + cc] = acc[a][c];
        }
    }
}

// ---- inverse along y + bias(mlp1_b) + gelu: X1 = gelu(invy(Hh2) + b1) ----
__global__ void __launch_bounds__(192) k_invy2(const float* __restrict__ Hh2f,
                                               const float2* __restrict__ Wy,
                                               const float* __restrict__ m1b, int layer,
                                               float* __restrict__ X1) {
    int bo = blockIdx.x;            // 0..1023
    int o = bo & 63;
    int y = threadIdx.x;            // active y<137
    int yc = (y < HH) ? y : (HH - 1);
    float wr[16], wi[16];
    #pragma unroll
    for (int ky = 0; ky < 16; ky++) {
        float2 w = Wy[yc * 16 + ky];
        wr[ky] = w.x; wi[ky] = w.y;
    }
    float b1 = m1b[layer * CH + o];
    const float* hbase = Hh2f + (size_t)bo * 4384;
    for (int x = 0; x < HH; x++) {
        const float* h = hbase + x * 32;
        float acc = b1;
        #pragma unroll
        for (int ky = 0; ky < 16; ky++)
            acc += h[2 * ky] * wr[ky] + h[2 * ky + 1] * wi[ky];
        if (y < HH) X1[(size_t)bo * NP + x * HH + y] = gelu_f(acc);
    }
}

// ---- tail GEMM1: Y = w2 . X1  (in-place: Y == X1, block-self-contained) ----
__global__ void __launch_bounds__(192) k_gemm1(const float* Xin, const float* __restrict__ w2,
                                               int layer, float* Yout) {
    __shared__ float sV[CH * PT];   // [i][p] 48KB
    __shared__ float sW[CH * 72];   // [i][o] 18KB
    int tid = threadIdx.x;
    int b = blockIdx.y;
    int s0 = blockIdx.x * PT;
    for (int idx = tid; idx < CH * PT; idx += 192) {
        int i = idx / PT, p = idx - i * PT;
        int s = s0 + p;
        sV[idx] = (s < NP) ? Xin[(size_t)(b * CH + i) * NP + s] : 0.f;
    }
    for (int idx = tid; idx < 4096; idx += 192) {
        int o = idx >> 6, i = idx & 63;
        sW[i * 72 + o] = w2[layer * 4096 + o * 64 + i];
    }
    __syncthreads();
    int og = tid & 7, pg = tid >> 3;
    int o0 = og * 8, p0 = pg * 8;
    float acc[8][8];
    #pragma unroll
    for (int a = 0; a < 8; a++)
        #pragma unroll
        for (int c = 0; c < 8; c++) acc[a][c] = 0.f;
    for (int i = 0; i < CH; i++) {
        float4 wA = *(const float4*)&sW[i * 72 + o0];
        float4 wB = *(const float4*)&sW[i * 72 + o0 + 4];
        float4 vA = *(const float4*)&sV[i * PT + p0];
        float4 vB = *(const float4*)&sV[i * PT + p0 + 4];
        float wv[8] = {wA.x, wA.y, wA.z, wA.w, wB.x, wB.y, wB.z, wB.w};
        float vv[8] = {vA.x, vA.y, vA.z, vA.w, vB.x, vB.y, vB.z, vB.w};
        #pragma unroll
        for (int a = 0; a < 8; a++)
            #pragma unroll
            for (int c = 0; c < 8; c++) acc[a][c] += wv[a] * vv[c];
    }
    #pragma unroll
    for (int a = 0; a < 8; a++) {
        size_t rowb = (size_t)(b * CH + o0 + a) * NP;
        #pragma unroll
        for (int c = 0; c < 8; c++) {
            int s = s0 + p0 + c;
            if (s < NP) Yout[rowb + s] = acc[a][c];
        }
    }
}

// ---- tail GEMM2 + skip + bias + gelu: X0 = gelu(Y + ww.X0 + b2 + wb), in-place on X0 ----
__global__ void __launch_bounds__(192) k_gemm2(float* X0, const float* __restrict__ Y,
                                               const float* __restrict__ wwp,
                                               const float* __restrict__ b2,
                                               const float* __restrict__ wb, int layer) {
    __shared__ float sV[CH * PT];
    __shared__ float sW[CH * 72];
    int tid = threadIdx.x;
    int b = blockIdx.y;
    int s0 = blockIdx.x * PT;
    for (int idx = tid; idx < CH * PT; idx += 192) {
        int i = idx / PT, p = idx - i * PT;
        int s = s0 + p;
        sV[idx] = (s < NP) ? X0[(size_t)(b * CH + i) * NP + s] : 0.f;
    }
    for (int idx = tid; idx < 4096; idx += 192) {
        int o = idx >> 6, i = idx & 63;
        sW[i * 72 + o] = wwp[layer * 4096 + o * 64 + i];
    }
    __syncthreads();
    int og = tid & 7, pg = tid >> 3;
    int o0 = og * 8, p0 = pg * 8;
    float acc[8][8];
    #pragma unroll
    for (int a = 0; a < 8; a++)
        #pragma unroll
        for (int c = 0; c < 8; c++) acc[a][c] = 0.f;
    for (int i = 0; i < CH; i++) {
        float4 wA = *(const float4*)&sW[i * 72 + o0];
        float4 wB = *(const float4*)&sW[i * 72 + o0 + 4];
        float4 vA = *(const float4*)&sV[i * PT + p0];
        float4 vB = *(const float4*)&sV[i * PT + p0 + 4];
        float wv[8] = {wA.x, wA.y, wA.z, wA.w, wB.x, wB.y, wB.z, wB.w};
        float vv[8] = {vA.x, vA.y, vA.z, vA.w, vB.x, vB.y, vB.z, vB.w};
        #pragma unroll
        for (int a = 0; a < 8; a++)
            #pragma unroll
            for (int c = 0; c < 8; c++) acc[a][c] += wv[a] * vv[c];
    }
    float bia[8];
    #pragma unroll
    for (int a = 0; a < 8; a++)
        bia[a] = b2[layer * CH + o0 + a] + wb[layer * CH + o0 + a];
    #pragma unroll
    for (int a = 0; a < 8; a++) {
        size_t rowb = (size_t)(b * CH + o0 + a) * NP;
        #pragma unroll
        for (int c = 0; c < 8; c++) {
            int s = s0 + p0 + c;
            if (s < NP) {
                float r = Y[rowb + s] + acc[a][c] + bia[a];
                X0[rowb + s] = gelu_f(r);
            }
        }
    }
}

// ---- final head ----
__global__ void __launch_bounds__(128) k_final2(const float* __restrict__ X0,
    const float* __restrict__ q1w, const float* __restrict__ q1b,
    const float* __restrict__ q2w, const float* __restrict__ q2b,
    float* __restrict__ out) {
    __shared__ float sV[CH * 128];    // [i][y] 32KB
    __shared__ float sW[CH * 72];     // [i][h] 18KB (per 64-hidden chunk)
    __shared__ float sRed[8 * 128];   // 4KB
    int tid = threadIdx.x;
    int b = blockIdx.y;
    int X = blockIdx.x;
    for (int idx = tid; idx < CH * 128; idx += 128) {
        int i = idx >> 7, y = idx & 127;
        sV[idx] = X0[(size_t)(b * CH + i) * NP + X * HH + y];
    }
    int hg = tid & 7, pg = tid >> 3;
    int h0 = hg * 8, y0 = pg * 8;
    float qacc[8];
    #pragma unroll
    for (int c = 0; c < 8; c++) qacc[c] = 0.f;
    for (int hc = 0; hc < 4; hc++) {
        for (int idx = tid; idx < 4096; idx += 128) {
            int h = idx >> 6, i = idx & 63;
            sW[i * 72 + h] = q1w[(hc * 64 + h) * 64 + i];
        }
        __syncthreads();
        float acc[8][8];
        #pragma unroll
        for (int a = 0; a < 8; a++)
            #pragma unroll
            for (int c = 0; c < 8; c++) acc[a][c] = 0.f;
        for (int i = 0; i < CH; i++) {
            float4 wA = *(const float4*)&sW[i * 72 + h0];
            float4 wB = *(const float4*)&sW[i * 72 + h0 + 4];
            float4 vA = *(const float4*)&sV[i * 128 + y0];
            float4 vB = *(const float4*)&sV[i * 128 + y0 + 4];
            float wv[8] = {wA.x, wA.y, wA.z, wA.w, wB.x, wB.y, wB.z, wB.w};
            float vv[8] = {vA.x, vA.y, vA.z, vA.w, vB.x, vB.y, vB.z, vB.w};
            #pragma unroll
            for (int a = 0; a < 8; a++)
                #pragma unroll
                for (int c = 0; c < 8; c++) acc[a][c] += wv[a] * vv[c];
        }
        #pragma unroll
        for (int a = 0; a < 8; a++) {
            int h = hc * 64 + h0 + a;
            float qb = q1b[h], q2v = q2w[h];
            #pragma unroll
            for (int c = 0; c < 8; c++)
                qacc[c] += q2v * gelu_f(acc[a][c] + qb);
        }
        __syncthreads();
    }
    #pragma unroll
    for (int c = 0; c < 8; c++) sRed[hg * 128 + y0 + c] = qacc[c];
    __syncthreads();
    if (tid < 128) {
        int y = tid;
        float r = q2b[0];
        #pragma unroll
        for (int g = 0; g < 8; g++) r += sRed[g * 128 + y];
        out[(b * SS + X) * SS + y] = r;
    }
}

extern "C" void kernel_launch(void* const* d_in, const int* in_sizes, int n_in,
                              void* d_out, int out_size, void* d_ws, size_t ws_size,
                              hipStream_t stream) {
    const float* x   = (const float*)d_in[0];
    const float* p_w = (const float*)d_in[1];
    const float* p_b = (const float*)d_in[2];
    const float* sw1 = (const float*)d_in[3];
    const float* sw2 = (const float*)d_in[4];
    const float* m1w = (const float*)d_in[5];
    const float* m1b = (const float*)d_in[6];
    const float* m2w = (const float*)d_in[7];
    const float* m2b = (const float*)d_in[8];
    const float* wwp = (const float*)d_in[9];
    const float* wbp = (const float*)d_in[10];
    const float* q1w = (const float*)d_in[11];
    const float* q1b = (const float*)d_in[12];
    const float* q2w = (const float*)d_in[13];
    const float* q2b = (const float*)d_in[14];

    float* ws = (float*)d_ws;
    float*  X0  = ws;                                      // B*CH*NP
    float*  X1  = X0 + (size_t)BB * CH * NP;               // B*CH*NP (doubles as Y)
    float2* T   = (float2*)(X1 + (size_t)BB * CH * NP);    // 140288*16
    float2* Hh  = T;                                       // alias: T dead after dftx
    float*  Hh2 = (float*)(T + (size_t)140288 * MM);       // 140288*16 cplx (float view)
    float2* F   = (float2*)(Hh2 + (size_t)140288 * MM * 2);
    float2* G   = F + (size_t)BB * CH * KK * MM;
    float2* Wy  = G + (size_t)BB * CH * KK * MM;
    float2* Wx  = Wy + HH * MM;

    k_init_twiddles<<<26, 256, 0, stream>>>(Wy, Wx);
    k_proj<<<(BB * CH * NP) / 256, 256, 0, stream>>>(x, p_w, p_b, X0);
    for (int layer = 0; layer < NL; layer++) {
        k_dfty2<<<548, 256, 0, stream>>>(X0, Wy, T);
        k_dftx<<<(BB * CH * KK * MM) / 256, 256, 0, stream>>>(T, Wx, F);
        k_specmul<<<(BB * CH * KK * MM) / 256, 256, 0, stream>>>(F, sw1, sw2, layer, G);
        k_invx<<<(BB * CH * HH * MM) / 256, 256, 0, stream>>>(G, Wx, Hh);
        k_mlp1s<<<dim3(35, BB), 128, 0, stream>>>((const float*)Hh, m1w, layer, Hh2);
        k_invy2<<<BB * CH, 192, 0, stream>>>(Hh2, Wy, m1b, layer, X1);
        k_gemm1<<<dim3(98, BB), 192, 0, stream>>>(X1, m2w, layer, X1);
        k_gemm2<<<dim3(98, BB), 192, 0, stream>>>(X0, X1, wwp, m2b, wbp, layer);
    }
    k_final2<<<dim3(SS, BB), 128, 0, stream>>>(X0, q1w, q1b, q2w, q2b, (float*)d_out);
}

// Round 3
// 2026.938 us; speedup vs baseline: 1.7313x; 1.5756x over previous
//
#include <hip/hip_runtime.h>
#include <math.h>

#define BB 16
#define CH 64
#define SS 128
#define HH 137
#define NP 18769    // 137*137
#define NPP 18816   // padded row stride (x64, = 147*128)
#define MM 16
#define KK 32
#define NL 4

__device__ __forceinline__ float gelu_f(float x) {
    return 0.5f * x * (1.0f + erff(x * 0.70710678118654752440f));
}

// ---- twiddle init ----
__global__ void k_init_twiddles(float2* __restrict__ Wy, float2* __restrict__ Wx) {
    int t = blockIdx.x * 256 + threadIdx.x;
    const double PI2 = 6.283185307179586476925286766559;
    if (t < HH * MM) {
        int y = t >> 4, k = t & 15;
        int m = (y * k) % HH;
        double ang = -PI2 * (double)m / (double)HH;
        Wy[t] = make_float2((float)cos(ang), (float)sin(ang));
    } else if (t < HH * MM + HH * KK) {
        int u = t - HH * MM;
        int x = u >> 5, ki = u & 31;
        int K = (ki < 16) ? ki : (105 + ki);
        int m = (x * K) % HH;
        double ang = -PI2 * (double)m / (double)HH;
        Wx[u] = make_float2((float)cos(ang), (float)sin(ang));
    }
}

// ---- projection into padded-stride X0 ----
__global__ void k_proj(const float* __restrict__ x, const float* __restrict__ pw,
                       const float* __restrict__ pb, float* __restrict__ X0) {
    int t = blockIdx.x * 256 + threadIdx.x;      // B*CH*NPP threads
    int b = t / (CH * NPP);
    int r = t - b * (CH * NPP);
    int d = r / NPP;
    int s = r - d * NPP;
    float v = 0.f;
    if (s < NP) {
        int X = s / HH, Y = s - X * HH;
        if (X < SS && Y < SS) {
            v = pb[d];
            #pragma unroll
            for (int c = 0; c < 5; c++)
                v += x[((b * 5 + c) * SS + X) * SS + Y] * pw[c * CH + d];
            v += ((float)X * (1.0f / 127.0f)) * pw[5 * CH + d];
            v += ((float)Y * (1.0f / 127.0f)) * pw[6 * CH + d];
        }
    }
    X0[t] = v;
}

// ---- forward DFT along y as GEMM: Tf[row][c32] = sum_y X0[row][y] * Wf[y][c] ----
__global__ void __launch_bounds__(256) k_dfty2g(const float* __restrict__ X0,
                                                const float2* __restrict__ Wy,
                                                float* __restrict__ Tf) {
    __shared__ float sXT[32 * 258];   // [yy][row] 33KB
    __shared__ float sWy[HH * 32];    // [y][32] re/im interleaved 17.5KB
    int tid = threadIdx.x;
    int r0b = blockIdx.x * 256;
    for (int idx = tid; idx < HH * MM; idx += 256) {
        float2 w = Wy[idx];
        sWy[idx * 2] = w.x;
        sWy[idx * 2 + 1] = w.y;
    }
    int rowg = tid >> 2, kg = tid & 3;
    int r0 = rowg * 4, k0 = kg * 8;
    float acc[4][8];
    #pragma unroll
    for (int a = 0; a < 4; a++)
        #pragma unroll
        for (int c = 0; c < 8; c++) acc[a][c] = 0.f;
    for (int yc = 0; yc < 5; yc++) {
        int y0c = yc * 32;
        int ylen = (y0c + 32 <= HH) ? 32 : (HH - y0c);
        __syncthreads();
        for (int idx = tid; idx < 256 * 32; idx += 256) {
            int r = idx >> 5, yy = idx & 31;
            int y = y0c + yy;
            int gr = r0b + r;
            unsigned bi = (unsigned)gr / 137u;
            int xx = gr - (int)bi * 137;
            sXT[yy * 258 + r] = (y < HH) ? X0[(size_t)bi * NPP + xx * HH + y] : 0.f;
        }
        __syncthreads();
        for (int yy = 0; yy < ylen; yy++) {
            int y = y0c + yy;
            float4 wA = *(const float4*)&sWy[y * 32 + k0];
            float4 wB = *(const float4*)&sWy[y * 32 + k0 + 4];
            float4 v  = *(const float4*)&sXT[yy * 258 + r0];
            float wv[8] = {wA.x, wA.y, wA.z, wA.w, wB.x, wB.y, wB.z, wB.w};
            float vv[4] = {v.x, v.y, v.z, v.w};
            #pragma unroll
            for (int a = 0; a < 4; a++)
                #pragma unroll
                for (int c = 0; c < 8; c++) acc[a][c] += vv[a] * wv[c];
        }
    }
    #pragma unroll
    for (int a = 0; a < 4; a++) {
        size_t rb = (size_t)(r0b + r0 + a) * 32 + k0;
        *(float4*)&Tf[rb]     = make_float4(acc[a][0], acc[a][1], acc[a][2], acc[a][3]);
        *(float4*)&Tf[rb + 4] = make_float4(acc[a][4], acc[a][5], acc[a][6], acc[a][7]);
    }
}

// ---- forward DFT along x ----
__global__ void k_dftx(const float2* __restrict__ T, const float2* __restrict__ Wx,
                       float2* __restrict__ F) {
    int t = blockIdx.x * 256 + threadIdx.x;
    int ky = t & 15;
    int kx = (t >> 4) & 31;
    int bi = t >> 9;
    float fr = 0.f, fi = 0.f;
    for (int x = 0; x < HH; x++) {
        float2 tv = T[(bi * HH + x) * MM + ky];
        float2 w = Wx[x * KK + kx];
        fr += tv.x * w.x - tv.y * w.y;
        fi += tv.x * w.y + tv.y * w.x;
    }
    F[t] = make_float2(fr, fi);
}

// ---- spectral multiply ----
__global__ void k_specmul(const float2* __restrict__ F, const float* __restrict__ sw1,
                          const float* __restrict__ sw2, int layer, float2* __restrict__ G) {
    int t = blockIdx.x * 256 + threadIdx.x;
    int ky = t & 15;
    int kx = (t >> 4) & 31;
    int o  = (t >> 9) & 63;
    int b  = t >> 15;
    const float* wb0;
    int kk;
    if (kx < 16) { wb0 = sw1; kk = kx; } else { wb0 = sw2; kk = kx - 16; }
    wb0 += layer * 2097152 + o * 256 + kk * 16 + ky;
    float gr = 0.f, gi = 0.f;
    for (int i = 0; i < CH; i++) {
        float2 f = F[((b * CH + i) * KK + kx) * MM + ky];
        float wr = wb0[i * 16384];
        float wi = wb0[i * 16384 + 1048576];
        gr += f.x * wr - f.y * wi;
        gi += f.x * wi + f.y * wr;
    }
    G[t] = make_float2(gr, gi);
}

// ---- mode-space mlp1: G2[b][p][m] = sum_o m1[p][o] * G[b][o][m] (1024 real cols/b) ----
__global__ void __launch_bounds__(128) k_mlp1m(const float* __restrict__ Gf,
                                               const float* __restrict__ m1w, int layer,
                                               float* __restrict__ G2f) {
    __shared__ float sG[64 * 64];   // [o][c] 16KB
    __shared__ float sM[64 * 68];   // [o][p] 17KB
    int tid = threadIdx.x;
    int b = blockIdx.y;
    int c0b = blockIdx.x * 64;
    for (int idx = tid; idx < 4096; idx += 128) {
        int o = idx >> 6, c = idx & 63;
        sG[idx] = Gf[(size_t)(b * CH + o) * 1024 + c0b + c];
    }
    for (int idx = tid; idx < 4096; idx += 128) {
        int p = idx >> 6, o = idx & 63;
        sM[o * 68 + p] = m1w[layer * 4096 + p * 64 + o];
    }
    __syncthreads();
    int cg = tid & 15, pg = tid >> 4;
    int c0 = cg * 4, p0 = pg * 8;
    float acc[8][4];
    #pragma unroll
    for (int a = 0; a < 8; a++)
        #pragma unroll
        for (int c = 0; c < 4; c++) acc[a][c] = 0.f;
    for (int o = 0; o < CH; o++) {
        float4 wA = *(const float4*)&sM[o * 68 + p0];
        float4 wB = *(const float4*)&sM[o * 68 + p0 + 4];
        float4 v  = *(const float4*)&sG[o * 64 + c0];
        float wv[8] = {wA.x, wA.y, wA.z, wA.w, wB.x, wB.y, wB.z, wB.w};
        float vv[4] = {v.x, v.y, v.z, v.w};
        #pragma unroll
        for (int a = 0; a < 8; a++)
            #pragma unroll
            for (int c = 0; c < 4; c++) acc[a][c] += wv[a] * vv[c];
    }
    #pragma unroll
    for (int a = 0; a < 8; a++)
        *(float4*)&G2f[(size_t)(b * CH + p0 + a) * 1024 + c0b + c0] =
            make_float4(acc[a][0], acc[a][1], acc[a][2], acc[a][3]);
}

// ---- inverse DFT along x ----
__global__ void k_invx(const float2* __restrict__ G, const float2* __restrict__ Wx,
                       float2* __restrict__ Hh) {
    int t = blockIdx.x * 256 + threadIdx.x;
    int ky = t & 15;
    int r = t >> 4;
    int x = r % HH;
    int bo = r / HH;
    float hr = 0.f, hi = 0.f;
    #pragma unroll 8
    for (int kx = 0; kx < KK; kx++) {
        float2 g = G[(bo * KK + kx) * MM + ky];
        float2 w = Wx[x * KK + kx];
        hr += g.x * w.x + g.y * w.y;
        hi += g.y * w.x - g.x * w.y;
    }
    float sc = (ky == 0 ? 1.0f : 2.0f) / 18769.0f;
    Hh[(bo * HH + x) * MM + ky] = make_float2(hr * sc, hi * sc);
}

// ---- inverse along y + bias + gelu ----
__global__ void __launch_bounds__(192) k_invy2b(const float* __restrict__ Hhf,
                                                const float2* __restrict__ Wy,
                                                const float* __restrict__ m1b, int layer,
                                                float* __restrict__ X1) {
    int bo = blockIdx.x;
    int o = bo & 63;
    int xh = blockIdx.y;
    int xs = xh * 69;
    int xe = xh ? HH : 69;
    int y = threadIdx.x;
    int yc = (y < HH) ? y : (HH - 1);
    float wr[16], wi[16];
    #pragma unroll
    for (int ky = 0; ky < 16; ky++) {
        float2 w = Wy[yc * 16 + ky];
        wr[ky] = w.x; wi[ky] = w.y;
    }
    float b1 = m1b[layer * CH + o];
    const float* hbase = Hhf + (size_t)bo * 4384;
    for (int x = xs; x < xe; x++) {
        const float* h = hbase + x * 32;
        float acc = b1;
        #pragma unroll
        for (int ky = 0; ky < 16; ky++)
            acc += h[2 * ky] * wr[ky] + h[2 * ky + 1] * wi[ky];
        if (y < HH) X1[(size_t)bo * NPP + x * HH + y] = gelu_f(acc);
    }
}

// ---- fused tail: X0 = gelu(w2.X1 + ww.X0 + b2 + wb) ----
__global__ void __launch_bounds__(256) k_tailf(float* __restrict__ X0, const float* __restrict__ X1,
    const float* __restrict__ w2, const float* __restrict__ wwp,
    const float* __restrict__ b2, const float* __restrict__ wb, int layer) {
    __shared__ float sV[CH * 128];   // 32KB
    __shared__ float sW[CH * 68];    // 17KB
    int tid = threadIdx.x;
    int b = blockIdx.y;
    int s0 = blockIdx.x * 128;
    int og = tid & 15, pg = tid >> 4;
    int o0 = og * 4, p0 = pg * 8;
    float acc[4][8];
    #pragma unroll
    for (int a = 0; a < 4; a++)
        #pragma unroll
        for (int c = 0; c < 8; c++) acc[a][c] = 0.f;

    // pass 1: w2 . X1
    for (int idx = tid; idx < 2048; idx += 256) {
        int i = idx >> 5, p4 = (idx & 31) * 4;
        *(float4*)&sV[i * 128 + p4] =
            *(const float4*)&X1[(size_t)(b * CH + i) * NPP + s0 + p4];
    }
    for (int idx = tid; idx < 4096; idx += 256) {
        int o = idx >> 6, i = idx & 63;
        sW[i * 68 + o] = w2[layer * 4096 + o * 64 + i];
    }
    __syncthreads();
    for (int i = 0; i < CH; i++) {
        float4 w  = *(const float4*)&sW[i * 68 + o0];
        float4 vA = *(const float4*)&sV[i * 128 + p0];
        float4 vB = *(const float4*)&sV[i * 128 + p0 + 4];
        float wv[4] = {w.x, w.y, w.z, w.w};
        float vv[8] = {vA.x, vA.y, vA.z, vA.w, vB.x, vB.y, vB.z, vB.w};
        #pragma unroll
        for (int a = 0; a < 4; a++)
            #pragma unroll
            for (int c = 0; c < 8; c++) acc[a][c] += wv[a] * vv[c];
    }
    __syncthreads();
    // pass 2: ww . X0
    for (int idx = tid; idx < 2048; idx += 256) {
        int i = idx >> 5, p4 = (idx & 31) * 4;
        *(float4*)&sV[i * 128 + p4] =
            *(const float4*)&X0[(size_t)(b * CH + i) * NPP + s0 + p4];
    }
    for (int idx = tid; idx < 4096; idx += 256) {
        int o = idx >> 6, i = idx & 63;
        sW[i * 68 + o] = wwp[layer * 4096 + o * 64 + i];
    }
    __syncthreads();
    for (int i = 0; i < CH; i++) {
        float4 w  = *(const float4*)&sW[i * 68 + o0];
        float4 vA = *(const float4*)&sV[i * 128 + p0];
        float4 vB = *(const float4*)&sV[i * 128 + p0 + 4];
        float wv[4] = {w.x, w.y, w.z, w.w};
        float vv[8] = {vA.x, vA.y, vA.z, vA.w, vB.x, vB.y, vB.z, vB.w};
        #pragma unroll
        for (int a = 0; a < 4; a++)
            #pragma unroll
            for (int c = 0; c < 8; c++) acc[a][c] += wv[a] * vv[c];
    }
    float bia[4];
    #pragma unroll
    for (int a = 0; a < 4; a++)
        bia[a] = b2[layer * CH + o0 + a] + wb[layer * CH + o0 + a];
    #pragma unroll
    for (int a = 0; a < 4; a++) {
        size_t rowb = (size_t)(b * CH + o0 + a) * NPP;
        #pragma unroll
        for (int c = 0; c < 8; c++) {
            int s = s0 + p0 + c;
            if (s < NP) X0[rowb + s] = gelu_f(acc[a][c] + bia[a]);
        }
    }
}

// ---- final head: crop + q1 + gelu + q2 ----
__global__ void __launch_bounds__(256) k_final3(const float* __restrict__ X0,
    const float* __restrict__ q1w, const float* __restrict__ q1b,
    const float* __restrict__ q2w, const float* __restrict__ q2b,
    float* __restrict__ out) {
    __shared__ float sV[CH * 128];   // 32KB
    __shared__ float sW[CH * 68];    // 17KB; sRed (16*132=2112 floats) aliases sW
    int tid = threadIdx.x;
    int b = blockIdx.y;
    int X = blockIdx.x;
    for (int idx = tid; idx < CH * 128; idx += 256) {
        int i = idx >> 7, y = idx & 127;
        sV[idx] = X0[(size_t)(b * CH + i) * NPP + X * HH + y];
    }
    int hg = tid & 15, yg = tid >> 4;
    int h0 = hg * 4, y0 = yg * 8;
    float qacc[8];
    #pragma unroll
    for (int c = 0; c < 8; c++) qacc[c] = 0.f;
    for (int hc = 0; hc < 4; hc++) {
        for (int idx = tid; idx < 4096; idx += 256) {
            int h = idx >> 6, i = idx & 63;
            sW[i * 68 + h] = q1w[(hc * 64 + h) * 64 + i];
        }
        __syncthreads();
        float acc[4][8];
        #pragma unroll
        for (int a = 0; a < 4; a++)
            #pragma unroll
            for (int c = 0; c < 8; c++) acc[a][c] = 0.f;
        for (int i = 0; i < CH; i++) {
            float4 w  = *(const float4*)&sW[i * 68 + h0];
            float4 vA = *(const float4*)&sV[i * 128 + y0];
            float4 vB = *(const float4*)&sV[i * 128 + y0 + 4];
            float wv[4] = {w.x, w.y, w.z, w.w};
            float vv[8] = {vA.x, vA.y, vA.z, vA.w, vB.x, vB.y, vB.z, vB.w};
            #pragma unroll
            for (int a = 0; a < 4; a++)
                #pragma unroll
                for (int c = 0; c < 8; c++) acc[a][c] += wv[a] * vv[c];
        }
        #pragma unroll
        for (int a = 0; a < 4; a++) {
            int h = hc * 64 + h0 + a;
            float qb = q1b[h], q2v = q2w[h];
            #pragma unroll
            for (int c = 0; c < 8; c++)
                qacc[c] += q2v * gelu_f(acc[a][c] + qb);
        }
        __syncthreads();
    }
    float* sRed = sW;
    *(float4*)&sRed[hg * 132 + y0]     = make_float4(qacc[0], qacc[1], qacc[2], qacc[3]);
    *(float4*)&sRed[hg * 132 + y0 + 4] = make_float4(qacc[4], qacc[5], qacc[6], qacc[7]);
    __syncthreads();
    if (tid < 128) {
        float r = q2b[0];
        #pragma unroll
        for (int g = 0; g < 16; g++) r += sRed[g * 132 + tid];
        out[(b * SS + X) * SS + tid] = r;
    }
}

extern "C" void kernel_launch(void* const* d_in, const int* in_sizes, int n_in,
                              void* d_out, int out_size, void* d_ws, size_t ws_size,
                              hipStream_t stream) {
    const float* x   = (const float*)d_in[0];
    const float* p_w = (const float*)d_in[1];
    const float* p_b = (const float*)d_in[2];
    const float* sw1 = (const float*)d_in[3];
    const float* sw2 = (const float*)d_in[4];
    const float* m1w = (const float*)d_in[5];
    const float* m1b = (const float*)d_in[6];
    const float* m2w = (const float*)d_in[7];
    const float* m2b = (const float*)d_in[8];
    const float* wwp = (const float*)d_in[9];
    const float* wbp = (const float*)d_in[10];
    const float* q1w = (const float*)d_in[11];
    const float* q1b = (const float*)d_in[12];
    const float* q2w = (const float*)d_in[13];
    const float* q2b = (const float*)d_in[14];

    float* ws = (float*)d_ws;
    float*  X0  = ws;                                      // B*CH*NPP
    float*  X1  = X0 + (size_t)BB * CH * NPP;              // B*CH*NPP
    float*  Tf  = X1 + (size_t)BB * CH * NPP;              // 140288*32 floats (T / Hh)
    float2* F   = (float2*)(Tf + (size_t)140288 * 32);     // 524288 f2 (F / G2)
    float2* G   = F + (size_t)524288;                      // 524288 f2
    float2* Wy  = G + (size_t)524288;
    float2* Wx  = Wy + HH * MM;

    k_init_twiddles<<<26, 256, 0, stream>>>(Wy, Wx);
    k_proj<<<(BB * CH * NPP) / 256, 256, 0, stream>>>(x, p_w, p_b, X0);
    for (int layer = 0; layer < NL; layer++) {
        k_dfty2g<<<548, 256, 0, stream>>>(X0, Wy, Tf);
        k_dftx<<<2048, 256, 0, stream>>>((const float2*)Tf, Wx, F);
        k_specmul<<<2048, 256, 0, stream>>>(F, sw1, sw2, layer, G);
        k_mlp1m<<<dim3(16, BB), 128, 0, stream>>>((const float*)G, m1w, layer, (float*)F);
        k_invx<<<8768, 256, 0, stream>>>(F, Wx, (float2*)Tf);
        k_invy2b<<<dim3(BB * CH, 2), 192, 0, stream>>>(Tf, Wy, m1b, layer, X1);
        k_tailf<<<dim3(147, BB), 256, 0, stream>>>(X0, X1, m2w, wwp, m2b, wbp, layer);
    }
    k_final3<<<dim3(SS, BB), 256, 0, stream>>>(X0, q1w, q1b, q2w, q2b, (float*)d_out);
}

// Round 4
// 1980.522 us; speedup vs baseline: 1.7719x; 1.0234x over previous
//
#include <hip/hip_runtime.h>
#include <math.h>

#define BB 16
#define CH 64
#define SS 128
#define HH 137
#define NP 18769    // 137*137
#define NPP 18816   // padded row stride
#define MM 16
#define KK 32
#define NL 4

__device__ __forceinline__ float gelu_f(float x) {
    return 0.5f * x * (1.0f + erff(x * 0.70710678118654752440f));
}

// ---- init: twiddles Wy, Wx, WyT (transposed) + transposed/fused tail weights ----
__global__ void k_init(float2* __restrict__ Wy, float2* __restrict__ Wx,
                       float2* __restrict__ WyT, float* __restrict__ wcomb,
                       const float* __restrict__ m2w, const float* __restrict__ wwp) {
    int t = blockIdx.x * 256 + threadIdx.x;
    const double PI2 = 6.283185307179586476925286766559;
    if (t < 2192) {                       // Wy[y*16+ky]
        int y = t >> 4, k = t & 15;
        int m = (y * k) % HH;
        double ang = -PI2 * (double)m / (double)HH;
        Wy[t] = make_float2((float)cos(ang), (float)sin(ang));
    } else if (t < 6576) {                // Wx[x*32+ki]
        int u = t - 2192;
        int x = u >> 5, ki = u & 31;
        int K = (ki < 16) ? ki : (105 + ki);
        int m = (x * K) % HH;
        double ang = -PI2 * (double)m / (double)HH;
        Wx[u] = make_float2((float)cos(ang), (float)sin(ang));
    } else if (t < 8768) {                // WyT[ky*137+y]
        int u = t - 6576;
        int ky = u / 137, y = u - ky * 137;
        int m = (y * ky) % HH;
        double ang = -PI2 * (double)m / (double)HH;
        WyT[u] = make_float2((float)cos(ang), (float)sin(ang));
    } else if (t < 41536) {               // wcomb[layer][i][0..63]=w2^T, [64..127]=ww^T
        int u = t - 8768;
        int layer = u >> 13;
        int r = u & 8191;
        int i = r >> 7, c = r & 127;
        float v;
        if (c < 64) v = m2w[layer * 4096 + c * 64 + i];
        else        v = wwp[layer * 4096 + (c - 64) * 64 + i];
        wcomb[u] = v;
    }
}

// ---- projection into padded-stride X0 ----
__global__ void k_proj(const float* __restrict__ x, const float* __restrict__ pw,
                       const float* __restrict__ pb, float* __restrict__ X0) {
    int t = blockIdx.x * 256 + threadIdx.x;
    int b = t / (CH * NPP);
    int r = t - b * (CH * NPP);
    int d = r / NPP;
    int s = r - d * NPP;
    float v = 0.f;
    if (s < NP) {
        int X = s / HH, Y = s - X * HH;
        if (X < SS && Y < SS) {
            v = pb[d];
            #pragma unroll
            for (int c = 0; c < 5; c++)
                v += x[((b * 5 + c) * SS + X) * SS + Y] * pw[c * CH + d];
            v += ((float)X * (1.0f / 127.0f)) * pw[5 * CH + d];
            v += ((float)Y * (1.0f / 127.0f)) * pw[6 * CH + d];
        }
    }
    X0[t] = v;
}

// ---- forward DFT along y as GEMM: Tf[row][32] ----
__global__ void __launch_bounds__(256) k_dfty2g(const float* __restrict__ X0,
                                                const float2* __restrict__ Wy,
                                                float* __restrict__ Tf) {
    __shared__ float sXT[32 * 258];
    __shared__ float sWy[HH * 32];
    int tid = threadIdx.x;
    int r0b = blockIdx.x * 256;
    for (int idx = tid; idx < HH * MM; idx += 256) {
        float2 w = Wy[idx];
        sWy[idx * 2] = w.x;
        sWy[idx * 2 + 1] = w.y;
    }
    int rowg = tid >> 2, kg = tid & 3;
    int r0 = rowg * 4, k0 = kg * 8;
    float acc[4][8];
    #pragma unroll
    for (int a = 0; a < 4; a++)
        #pragma unroll
        for (int c = 0; c < 8; c++) acc[a][c] = 0.f;
    for (int yc = 0; yc < 5; yc++) {
        int y0c = yc * 32;
        int ylen = (y0c + 32 <= HH) ? 32 : (HH - y0c);
        __syncthreads();
        for (int idx = tid; idx < 256 * 32; idx += 256) {
            int r = idx >> 5, yy = idx & 31;
            int y = y0c + yy;
            int gr = r0b + r;
            unsigned bi = (unsigned)gr / 137u;
            int xx = gr - (int)bi * 137;
            sXT[yy * 258 + r] = (y < HH) ? X0[(size_t)bi * NPP + xx * HH + y] : 0.f;
        }
        __syncthreads();
        for (int yy = 0; yy < ylen; yy++) {
            int y = y0c + yy;
            float4 wA = *(const float4*)&sWy[y * 32 + k0];
            float4 wB = *(const float4*)&sWy[y * 32 + k0 + 4];
            float4 v  = *(const float4*)&sXT[yy * 258 + r0];
            float wv[8] = {wA.x, wA.y, wA.z, wA.w, wB.x, wB.y, wB.z, wB.w};
            float vv[4] = {v.x, v.y, v.z, v.w};
            #pragma unroll
            for (int a = 0; a < 4; a++)
                #pragma unroll
                for (int c = 0; c < 8; c++) acc[a][c] += vv[a] * wv[c];
        }
    }
    #pragma unroll
    for (int a = 0; a < 4; a++) {
        size_t rb = (size_t)(r0b + r0 + a) * 32 + k0;
        *(float4*)&Tf[rb]     = make_float4(acc[a][0], acc[a][1], acc[a][2], acc[a][3]);
        *(float4*)&Tf[rb + 4] = make_float4(acc[a][4], acc[a][5], acc[a][6], acc[a][7]);
    }
}

// ---- forward DFT along x: LDS-staged per (b,i) ----
__global__ void __launch_bounds__(512) k_dftx2(const float* __restrict__ Tf,
                                               const float2* __restrict__ Wx,
                                               float2* __restrict__ F) {
    __shared__ float sT[HH * 32];       // 17.5KB
    __shared__ float2 sWx[HH * 32];     // 35KB
    int tid = threadIdx.x;
    int bi = blockIdx.x;
    const float4* tg = (const float4*)(Tf + (size_t)bi * (HH * 32));
    for (int idx = tid; idx < HH * 8; idx += 512) ((float4*)sT)[idx] = tg[idx];
    const float4* wg = (const float4*)Wx;
    for (int idx = tid; idx < HH * 16; idx += 512) ((float4*)sWx)[idx] = wg[idx];
    __syncthreads();
    int ky = tid & 15, kx = tid >> 4;
    float fr = 0.f, fi = 0.f;
    const float2* sT2 = (const float2*)sT;
    #pragma unroll 4
    for (int x = 0; x < HH; x++) {
        float2 t = sT2[x * 16 + ky];
        float2 w = sWx[x * 32 + kx];
        fr += t.x * w.x - t.y * w.y;
        fi += t.x * w.y + t.y * w.x;
    }
    F[(size_t)bi * 512 + tid] = make_float2(fr, fi);
}

// ---- spectral multiply ----
__global__ void k_specmul(const float2* __restrict__ F, const float* __restrict__ sw1,
                          const float* __restrict__ sw2, int layer, float2* __restrict__ G) {
    int t = blockIdx.x * 256 + threadIdx.x;
    int ky = t & 15;
    int kx = (t >> 4) & 31;
    int o  = (t >> 9) & 63;
    int b  = t >> 15;
    const float* wb0;
    int kk;
    if (kx < 16) { wb0 = sw1; kk = kx; } else { wb0 = sw2; kk = kx - 16; }
    wb0 += layer * 2097152 + o * 256 + kk * 16 + ky;
    float gr = 0.f, gi = 0.f;
    for (int i = 0; i < CH; i++) {
        float2 f = F[((b * CH + i) * KK + kx) * MM + ky];
        float wr = wb0[i * 16384];
        float wi = wb0[i * 16384 + 1048576];
        gr += f.x * wr - f.y * wi;
        gi += f.x * wi + f.y * wr;
    }
    G[t] = make_float2(gr, gi);
}

// ---- mode-space mlp1 ----
__global__ void __launch_bounds__(128) k_mlp1m(const float* __restrict__ Gf,
                                               const float* __restrict__ m1w, int layer,
                                               float* __restrict__ G2f) {
    __shared__ float sG[64 * 64];
    __shared__ float sM[64 * 68];
    int tid = threadIdx.x;
    int b = blockIdx.y;
    int c0b = blockIdx.x * 64;
    for (int idx = tid; idx < 4096; idx += 128) {
        int o = idx >> 6, c = idx & 63;
        sG[idx] = Gf[(size_t)(b * CH + o) * 1024 + c0b + c];
    }
    for (int idx = tid; idx < 4096; idx += 128) {
        int p = idx >> 6, o = idx & 63;
        sM[o * 68 + p] = m1w[layer * 4096 + p * 64 + o];
    }
    __syncthreads();
    int cg = tid & 15, pg = tid >> 4;
    int c0 = cg * 4, p0 = pg * 8;
    float acc[8][4];
    #pragma unroll
    for (int a = 0; a < 8; a++)
        #pragma unroll
        for (int c = 0; c < 4; c++) acc[a][c] = 0.f;
    for (int o = 0; o < CH; o++) {
        float4 wA = *(const float4*)&sM[o * 68 + p0];
        float4 wB = *(const float4*)&sM[o * 68 + p0 + 4];
        float4 v  = *(const float4*)&sG[o * 64 + c0];
        float wv[8] = {wA.x, wA.y, wA.z, wA.w, wB.x, wB.y, wB.z, wB.w};
        float vv[4] = {v.x, v.y, v.z, v.w};
        #pragma unroll
        for (int a = 0; a < 8; a++)
            #pragma unroll
            for (int c = 0; c < 4; c++) acc[a][c] += wv[a] * vv[c];
    }
    #pragma unroll
    for (int a = 0; a < 8; a++)
        *(float4*)&G2f[(size_t)(b * CH + p0 + a) * 1024 + c0b + c0] =
            make_float4(acc[a][0], acc[a][1], acc[a][2], acc[a][3]);
}

// ---- inverse DFT along x: LDS-staged per (b,o); writes Hh[bo][x][ky] ----
__global__ void __launch_bounds__(256) k_invx2(const float2* __restrict__ G2,
                                               const float2* __restrict__ Wx,
                                               float2* __restrict__ Hh) {
    __shared__ float2 sG[512];          // 4KB
    __shared__ float2 sWx[HH * 32];     // 35KB
    int tid = threadIdx.x;
    int bo = blockIdx.x;
    const float4* gg = (const float4*)(G2 + (size_t)bo * 512);
    if (tid < 256) ((float4*)sG)[tid] = gg[tid];
    const float4* wg = (const float4*)Wx;
    for (int idx = tid; idx < HH * 16; idx += 256) ((float4*)sWx)[idx] = wg[idx];
    __syncthreads();
    for (int it = 0; it < 9; it++) {
        int item = it * 256 + tid;
        if (item >= HH * 16) break;
        int x = item >> 4, ky = item & 15;
        float hr = 0.f, hi = 0.f;
        #pragma unroll 4
        for (int kx = 0; kx < KK; kx++) {
            float2 g = sG[kx * 16 + ky];
            float2 w = sWx[x * 32 + kx];
            hr += g.x * w.x + g.y * w.y;
            hi += g.y * w.x - g.x * w.y;
        }
        float sc = (ky == 0 ? 1.0f : 2.0f) / 18769.0f;
        Hh[(size_t)bo * (HH * 16) + item] = make_float2(hr * sc, hi * sc);
    }
}

// ---- fused: inv-y + mlp1 bias + gelu + mlp2 + skip-conv + bias + gelu, in-place X0 ----
// block = (x-row, b); lane = y; weights wave-uniform (s_load)
__global__ void __launch_bounds__(192) k_fuse(float* __restrict__ X0,
    const float2* __restrict__ Hh, const float2* __restrict__ WyT,
    const float* __restrict__ wcomb, const float* __restrict__ m1b,
    const float* __restrict__ m2b, const float* __restrict__ wb, int layer) {
    int tid = threadIdx.x;
    int x = blockIdx.x;
    int b = blockIdx.y;
    int yy = (tid < HH) ? tid : (HH - 1);
    float wr[16], wi[16];
    #pragma unroll
    for (int ky = 0; ky < 16; ky++) {
        float2 w = WyT[ky * HH + yy];
        wr[ky] = w.x; wi[ky] = w.y;
    }
    float acc[64];
    #pragma unroll
    for (int o = 0; o < 64; o++) acc[o] = 0.f;
    const float* wl = wcomb + layer * 8192;
    for (int i = 0; i < CH; i++) {
        const float4* h4 = (const float4*)(Hh + ((size_t)(b * CH + i) * HH + x) * 16);
        float x1 = m1b[layer * CH + i];
        #pragma unroll
        for (int j = 0; j < 8; j++) {
            float4 a = h4[j];
            x1 += a.x * wr[2 * j] + a.y * wi[2 * j] + a.z * wr[2 * j + 1] + a.w * wi[2 * j + 1];
        }
        x1 = gelu_f(x1);
        float x0 = X0[(size_t)(b * CH + i) * NPP + x * HH + yy];
        const float4* wc = (const float4*)(wl + i * 128);
        #pragma unroll
        for (int oq = 0; oq < 16; oq++) {
            float4 wa = wc[oq];
            float4 wsk = wc[16 + oq];
            acc[4 * oq + 0] += wa.x * x1 + wsk.x * x0;
            acc[4 * oq + 1] += wa.y * x1 + wsk.y * x0;
            acc[4 * oq + 2] += wa.z * x1 + wsk.z * x0;
            acc[4 * oq + 3] += wa.w * x1 + wsk.w * x0;
        }
    }
    bool act = (tid < HH);
    #pragma unroll
    for (int o = 0; o < 64; o++) {
        float bias = m2b[layer * CH + o] + wb[layer * CH + o];
        float r = gelu_f(acc[o] + bias);
        if (act) X0[(size_t)(b * CH + o) * NPP + x * HH + tid] = r;
    }
}

// ---- final head: register-resident channels, uniform q1w rows, no LDS ----
__global__ void __launch_bounds__(128) k_final4(const float* __restrict__ X0,
    const float* __restrict__ q1w, const float* __restrict__ q1b,
    const float* __restrict__ q2w, const float* __restrict__ q2b,
    float* __restrict__ out) {
    int y = threadIdx.x;       // 0..127
    int X = blockIdx.x;
    int b = blockIdx.y;
    float v[64];
    #pragma unroll
    for (int i = 0; i < 64; i++)
        v[i] = X0[(size_t)(b * CH + i) * NPP + X * HH + y];
    float qacc = 0.f;
    for (int h = 0; h < 256; h++) {
        const float4* qw = (const float4*)(q1w + h * 64);
        float s0 = q1b[h], s1 = 0.f, s2 = 0.f, s3 = 0.f;
        #pragma unroll
        for (int j = 0; j < 16; j += 4) {
            float4 w0 = qw[j], w1 = qw[j + 1], w2 = qw[j + 2], w3 = qw[j + 3];
            s0 += w0.x * v[4*j+0] + w0.y * v[4*j+1] + w0.z * v[4*j+2] + w0.w * v[4*j+3];
            s1 += w1.x * v[4*j+4] + w1.y * v[4*j+5] + w1.z * v[4*j+6] + w1.w * v[4*j+7];
            s2 += w2.x * v[4*j+8] + w2.y * v[4*j+9] + w2.z * v[4*j+10] + w2.w * v[4*j+11];
            s3 += w3.x * v[4*j+12] + w3.y * v[4*j+13] + w3.z * v[4*j+14] + w3.w * v[4*j+15];
        }
        float hv = (s0 + s1) + (s2 + s3);
        qacc += q2w[h] * gelu_f(hv);
    }
    out[(b * SS + X) * SS + y] = qacc + q2b[0];
}

extern "C" void kernel_launch(void* const* d_in, const int* in_sizes, int n_in,
                              void* d_out, int out_size, void* d_ws, size_t ws_size,
                              hipStream_t stream) {
    const float* x   = (const float*)d_in[0];
    const float* p_w = (const float*)d_in[1];
    const float* p_b = (const float*)d_in[2];
    const float* sw1 = (const float*)d_in[3];
    const float* sw2 = (const float*)d_in[4];
    const float* m1w = (const float*)d_in[5];
    const float* m1b = (const float*)d_in[6];
    const float* m2w = (const float*)d_in[7];
    const float* m2b = (const float*)d_in[8];
    const float* wwp = (const float*)d_in[9];
    const float* wbp = (const float*)d_in[10];
    const float* q1w = (const float*)d_in[11];
    const float* q1b = (const float*)d_in[12];
    const float* q2w = (const float*)d_in[13];
    const float* q2b = (const float*)d_in[14];

    float* ws = (float*)d_ws;
    float*  X0   = ws;                                   // 19,267,584 floats
    float*  Tf   = X0 + (size_t)BB * CH * NPP;           // 4,489,216 floats (T / Hh)
    float2* F    = (float2*)(Tf + (size_t)140288 * 32);  // 524,288 f2 (F / G2)
    float2* G    = F + (size_t)524288;                   // 524,288 f2
    float2* Wy   = G + (size_t)524288;                   // 2192 f2
    float2* Wx   = Wy + 2192;                            // 4384 f2
    float2* WyT  = Wx + 4384;                            // 2192 f2
    float*  wcomb = (float*)(WyT + 2192);                // 32768 floats

    k_init<<<163, 256, 0, stream>>>(Wy, Wx, WyT, wcomb, m2w, wwp);
    k_proj<<<(BB * CH * NPP) / 256, 256, 0, stream>>>(x, p_w, p_b, X0);
    for (int layer = 0; layer < NL; layer++) {
        k_dfty2g<<<548, 256, 0, stream>>>(X0, Wy, Tf);
        k_dftx2<<<1024, 512, 0, stream>>>(Tf, Wx, F);
        k_specmul<<<2048, 256, 0, stream>>>(F, sw1, sw2, layer, G);
        k_mlp1m<<<dim3(16, BB), 128, 0, stream>>>((const float*)G, m1w, layer, (float*)F);
        k_invx2<<<1024, 256, 0, stream>>>(F, Wx, (float2*)Tf);
        k_fuse<<<dim3(HH, BB), 192, 0, stream>>>(X0, (const float2*)Tf, WyT, wcomb,
                                                 m1b, m2b, wbp, layer);
    }
    k_final4<<<dim3(SS, BB), 128, 0, stream>>>(X0, q1w, q1b, q2w, q2b, (float*)d_out);
}

// Round 5
// 1689.185 us; speedup vs baseline: 2.0775x; 1.1725x over previous
//
#include <hip/hip_runtime.h>
#include <math.h>

#define BB 16
#define CH 64
#define SS 128
#define HH 137
#define XS 144            // padded x-stride of X0 rows (16B-aligned)
#define CS (137 * 144)    // per-channel stride = 19728
#define MM 16
#define KK 32
#define NL 4

__device__ __forceinline__ float gelu_f(float x) {
    return 0.5f * x * (1.0f + erff(x * 0.70710678118654752440f));
}

// ---- init: twiddles + fused tail weights ----
__global__ void k_init(float2* __restrict__ Wy, float2* __restrict__ Wx,
                       float2* __restrict__ WyT, float* __restrict__ wcomb,
                       const float* __restrict__ m2w, const float* __restrict__ wwp) {
    int t = blockIdx.x * 256 + threadIdx.x;
    const double PI2 = 6.283185307179586476925286766559;
    if (t < 2192) {                       // Wy[y*16+ky]
        int y = t >> 4, k = t & 15;
        int m = (y * k) % HH;
        double ang = -PI2 * (double)m / (double)HH;
        Wy[t] = make_float2((float)cos(ang), (float)sin(ang));
    } else if (t < 6576) {                // Wx[x*32+ki]
        int u = t - 2192;
        int x = u >> 5, ki = u & 31;
        int K = (ki < 16) ? ki : (105 + ki);
        int m = (x * K) % HH;
        double ang = -PI2 * (double)m / (double)HH;
        Wx[u] = make_float2((float)cos(ang), (float)sin(ang));
    } else if (t < 8768) {                // WyT[ky*137+y]
        int u = t - 6576;
        int ky = u / 137, y = u - ky * 137;
        int m = (y * ky) % HH;
        double ang = -PI2 * (double)m / (double)HH;
        WyT[u] = make_float2((float)cos(ang), (float)sin(ang));
    } else if (t < 41536) {               // wcomb[layer][i][0..63]=w2^T, [64..127]=ww^T
        int u = t - 8768;
        int layer = u >> 13;
        int r = u & 8191;
        int i = r >> 7, c = r & 127;
        float v;
        if (c < 64) v = m2w[layer * 4096 + c * 64 + i];
        else        v = wwp[layer * 4096 + (c - 64) * 64 + i];
        wcomb[u] = v;
    }
}

// ---- per-layer spectral-weight transpose: WS[kx][ky][i][o] (float2 re/im) ----
// dst-linear (coalesced writes), scattered reads
__global__ void k_wtrans(const float* __restrict__ sw1, const float* __restrict__ sw2,
                         int layer, float* __restrict__ WS) {
    int d = blockIdx.x * 256 + threadIdx.x;     // 4,194,304 floats
    int reim = d & 1;
    int o  = (d >> 1) & 63;
    int i  = (d >> 7) & 63;
    int ky = (d >> 13) & 15;
    int kx = (d >> 17) & 31;
    const float* src = (kx < 16) ? sw1 : sw2;
    int kk = kx & 15;
    WS[d] = src[layer * 2097152 + reim * 1048576 + i * 16384 + o * 256 + kk * 16 + ky];
}

// ---- projection into padded X0 ----
__global__ void k_proj(const float* __restrict__ x, const float* __restrict__ pw,
                       const float* __restrict__ pb, float* __restrict__ X0) {
    int t = blockIdx.x * 256 + threadIdx.x;     // B*CH*CS threads
    int b = t / (CH * CS);
    int r = t - b * (CH * CS);
    int d = r / CS;
    int s = r - d * CS;
    int X = s / XS, Y = s - X * XS;
    float v = 0.f;
    if (X < SS && Y < SS) {
        v = pb[d];
        #pragma unroll
        for (int c = 0; c < 5; c++)
            v += x[((b * 5 + c) * SS + X) * SS + Y] * pw[c * CH + d];
        v += ((float)X * (1.0f / 127.0f)) * pw[5 * CH + d];
        v += ((float)Y * (1.0f / 127.0f)) * pw[6 * CH + d];
    }
    X0[t] = v;
}

// ---- forward DFT along y: coalesced float4 staging + scatter LDS transpose ----
// T[row][32], row = bi*137 + x
__global__ void __launch_bounds__(256) k_dfty3(const float* __restrict__ X0,
                                               const float2* __restrict__ Wy,
                                               float* __restrict__ Tf) {
    __shared__ float sXT[32 * 260];   // [yy][r], stride 260 (16B-aligned, scrambled banks)
    __shared__ float sWy[HH * 32];
    int tid = threadIdx.x;
    int r0b = blockIdx.x * 256;
    int bi0 = r0b / 137;
    int xx0 = r0b - bi0 * 137;
    for (int idx = tid; idx < HH * MM; idx += 256) {
        float2 w = Wy[idx];
        sWy[idx * 2] = w.x;
        sWy[idx * 2 + 1] = w.y;
    }
    int rowg = tid >> 2, kg = tid & 3;
    int r0 = rowg * 4, k0 = kg * 8;
    float acc[4][8];
    #pragma unroll
    for (int a = 0; a < 4; a++)
        #pragma unroll
        for (int c = 0; c < 8; c++) acc[a][c] = 0.f;
    for (int yc = 0; yc < 5; yc++) {
        int y0c = yc * 32;
        int ylen = (y0c + 32 <= HH) ? 32 : (HH - y0c);
        __syncthreads();
        // stage: 2048 float4 slots, coalesced global reads, scatter LDS writes
        for (int k = 0; k < 8; k++) {
            int idx = k * 256 + tid;
            int r = idx >> 3, q = idx & 7;
            int xx = xx0 + r, bi = bi0;
            if (xx >= 137) { xx -= 137; bi++; }
            if (xx >= 137) { xx -= 137; bi++; }
            int y = y0c + 4 * q;
            size_t off = (size_t)bi * CS + xx * XS + y;
            float4 v;
            if (y + 4 <= HH) {
                v = *(const float4*)&X0[off];
            } else {
                v.x = (y     < HH) ? X0[off]     : 0.f;
                v.y = (y + 1 < HH) ? X0[off + 1] : 0.f;
                v.z = (y + 2 < HH) ? X0[off + 2] : 0.f;
                v.w = (y + 3 < HH) ? X0[off + 3] : 0.f;
            }
            int yy = 4 * q;
            sXT[(yy    ) * 260 + r] = v.x;
            sXT[(yy + 1) * 260 + r] = v.y;
            sXT[(yy + 2) * 260 + r] = v.z;
            sXT[(yy + 3) * 260 + r] = v.w;
        }
        __syncthreads();
        for (int yy = 0; yy < ylen; yy++) {
            int y = y0c + yy;
            float4 wA = *(const float4*)&sWy[y * 32 + k0];
            float4 wB = *(const float4*)&sWy[y * 32 + k0 + 4];
            float4 v  = *(const float4*)&sXT[yy * 260 + r0];
            float wv[8] = {wA.x, wA.y, wA.z, wA.w, wB.x, wB.y, wB.z, wB.w};
            float vv[4] = {v.x, v.y, v.z, v.w};
            #pragma unroll
            for (int a = 0; a < 4; a++)
                #pragma unroll
                for (int c = 0; c < 8; c++) acc[a][c] += vv[a] * wv[c];
        }
    }
    #pragma unroll
    for (int a = 0; a < 4; a++) {
        size_t rb = (size_t)(r0b + r0 + a) * 32 + k0;
        *(float4*)&Tf[rb]     = make_float4(acc[a][0], acc[a][1], acc[a][2], acc[a][3]);
        *(float4*)&Tf[rb + 4] = make_float4(acc[a][4], acc[a][5], acc[a][6], acc[a][7]);
    }
}

// ---- forward DFT along x: LDS-staged per (b,i) ----
__global__ void __launch_bounds__(512) k_dftx2(const float* __restrict__ Tf,
                                               const float2* __restrict__ Wx,
                                               float2* __restrict__ F) {
    __shared__ float sT[HH * 32];
    __shared__ float2 sWx[HH * 32];
    int tid = threadIdx.x;
    int bi = blockIdx.x;
    const float4* tg = (const float4*)(Tf + (size_t)bi * (HH * 32));
    for (int idx = tid; idx < HH * 8; idx += 512) ((float4*)sT)[idx] = tg[idx];
    const float4* wg = (const float4*)Wx;
    for (int idx = tid; idx < HH * 16; idx += 512) ((float4*)sWx)[idx] = wg[idx];
    __syncthreads();
    int ky = tid & 15, kx = tid >> 4;
    float fr = 0.f, fi = 0.f;
    const float2* sT2 = (const float2*)sT;
    #pragma unroll 4
    for (int x = 0; x < HH; x++) {
        float2 t = sT2[x * 16 + ky];
        float2 w = sWx[x * 32 + kx];
        fr += t.x * w.x - t.y * w.y;
        fi += t.x * w.y + t.y * w.x;
    }
    F[(size_t)bi * 512 + tid] = make_float2(fr, fi);
}

// ---- spectral multiply with transposed weights; lanes = o (coalesced), F scalar ----
__global__ void __launch_bounds__(256) k_specmul2(const float2* __restrict__ F,
                                                  const float2* __restrict__ WS,
                                                  float2* __restrict__ G) {
    int tid = threadIdx.x;
    int o = tid & 63;
    int kyq = __builtin_amdgcn_readfirstlane(tid >> 6);   // wave-uniform
    int kx = blockIdx.x;
    int bg = blockIdx.y;
    for (int bq = 0; bq < 2; bq++) {
        int b = bg * 2 + bq;
        float gr[4], gi[4];
        #pragma unroll
        for (int j = 0; j < 4; j++) { gr[j] = 0.f; gi[j] = 0.f; }
        for (int i = 0; i < CH; i++) {
            const float2* Fb = F + ((size_t)(b * CH + i) * KK + kx) * MM + kyq * 4;
            const float2* Wb = WS + ((size_t)(kx * MM + kyq * 4) * CH + i) * CH + o;
            #pragma unroll
            for (int j = 0; j < 4; j++) {
                float2 f = Fb[j];
                float2 w = Wb[(size_t)j * CH * CH];
                gr[j] += f.x * w.x - f.y * w.y;
                gi[j] += f.x * w.y + f.y * w.x;
            }
        }
        float* Gf = (float*)G;
        size_t base = (((size_t)(b * CH + o) * KK + kx) * MM + kyq * 4) * 2;
        *(float4*)&Gf[base]     = make_float4(gr[0], gi[0], gr[1], gi[1]);
        *(float4*)&Gf[base + 4] = make_float4(gr[2], gi[2], gr[3], gi[3]);
    }
}

// ---- mode-space mlp1 ----
__global__ void __launch_bounds__(128) k_mlp1m(const float* __restrict__ Gf,
                                               const float* __restrict__ m1w, int layer,
                                               float* __restrict__ G2f) {
    __shared__ float sG[64 * 64];
    __shared__ float sM[64 * 68];
    int tid = threadIdx.x;
    int b = blockIdx.y;
    int c0b = blockIdx.x * 64;
    for (int idx = tid; idx < 4096; idx += 128) {
        int o = idx >> 6, c = idx & 63;
        sG[idx] = Gf[(size_t)(b * CH + o) * 1024 + c0b + c];
    }
    for (int idx = tid; idx < 4096; idx += 128) {
        int p = idx >> 6, o = idx & 63;
        sM[o * 68 + p] = m1w[layer * 4096 + p * 64 + o];
    }
    __syncthreads();
    int cg = tid & 15, pg = tid >> 4;
    int c0 = cg * 4, p0 = pg * 8;
    float acc[8][4];
    #pragma unroll
    for (int a = 0; a < 8; a++)
        #pragma unroll
        for (int c = 0; c < 4; c++) acc[a][c] = 0.f;
    for (int o = 0; o < CH; o++) {
        float4 wA = *(const float4*)&sM[o * 68 + p0];
        float4 wB = *(const float4*)&sM[o * 68 + p0 + 4];
        float4 v  = *(const float4*)&sG[o * 64 + c0];
        float wv[8] = {wA.x, wA.y, wA.z, wA.w, wB.x, wB.y, wB.z, wB.w};
        float vv[4] = {v.x, v.y, v.z, v.w};
        #pragma unroll
        for (int a = 0; a < 8; a++)
            #pragma unroll
            for (int c = 0; c < 4; c++) acc[a][c] += wv[a] * vv[c];
    }
    #pragma unroll
    for (int a = 0; a < 8; a++)
        *(float4*)&G2f[(size_t)(b * CH + p0 + a) * 1024 + c0b + c0] =
            make_float4(acc[a][0], acc[a][1], acc[a][2], acc[a][3]);
}

// ---- inverse DFT along x: LDS-staged per (b,o) ----
__global__ void __launch_bounds__(256) k_invx2(const float2* __restrict__ G2,
                                               const float2* __restrict__ Wx,
                                               float2* __restrict__ Hh) {
    __shared__ float2 sG[512];
    __shared__ float2 sWx[HH * 32];
    int tid = threadIdx.x;
    int bo = blockIdx.x;
    const float4* gg = (const float4*)(G2 + (size_t)bo * 512);
    if (tid < 256) ((float4*)sG)[tid] = gg[tid];
    const float4* wg = (const float4*)Wx;
    for (int idx = tid; idx < HH * 16; idx += 256) ((float4*)sWx)[idx] = wg[idx];
    __syncthreads();
    for (int it = 0; it < 9; it++) {
        int item = it * 256 + tid;
        if (item >= HH * 16) break;
        int x = item >> 4, ky = item & 15;
        float hr = 0.f, hi = 0.f;
        #pragma unroll 4
        for (int kx = 0; kx < KK; kx++) {
            float2 g = sG[kx * 16 + ky];
            float2 w = sWx[x * 32 + kx];
            hr += g.x * w.x + g.y * w.y;
            hi += g.y * w.x - g.x * w.y;
        }
        float sc = (ky == 0 ? 1.0f : 2.0f) / 18769.0f;
        Hh[(size_t)bo * (HH * 16) + item] = make_float2(hr * sc, hi * sc);
    }
}

// ---- fused: inv-y + gelu(mlp1) + mlp2 + skip + gelu, in-place X0 ----
__global__ void __launch_bounds__(192) k_fuse(float* __restrict__ X0,
    const float2* __restrict__ Hh, const float2* __restrict__ WyT,
    const float* __restrict__ wcomb, const float* __restrict__ m1b,
    const float* __restrict__ m2b, const float* __restrict__ wb, int layer) {
    int tid = threadIdx.x;
    int x = blockIdx.x;
    int b = blockIdx.y;
    int yy = (tid < HH) ? tid : (HH - 1);
    float wr[16], wi[16];
    #pragma unroll
    for (int ky = 0; ky < 16; ky++) {
        float2 w = WyT[ky * HH + yy];
        wr[ky] = w.x; wi[ky] = w.y;
    }
    float acc[64];
    #pragma unroll
    for (int o = 0; o < 64; o++) acc[o] = 0.f;
    const float* wl = wcomb + layer * 8192;
    for (int i = 0; i < CH; i++) {
        const float4* h4 = (const float4*)(Hh + ((size_t)(b * CH + i) * HH + x) * 16);
        float x1 = m1b[layer * CH + i];
        #pragma unroll
        for (int j = 0; j < 8; j++) {
            float4 a = h4[j];
            x1 += a.x * wr[2 * j] + a.y * wi[2 * j] + a.z * wr[2 * j + 1] + a.w * wi[2 * j + 1];
        }
        x1 = gelu_f(x1);
        float x0 = X0[(size_t)(b * CH + i) * CS + x * XS + yy];
        const float4* wc = (const float4*)(wl + i * 128);
        #pragma unroll
        for (int oq = 0; oq < 16; oq++) {
            float4 wa = wc[oq];
            float4 wsk = wc[16 + oq];
            acc[4 * oq + 0] += wa.x * x1 + wsk.x * x0;
            acc[4 * oq + 1] += wa.y * x1 + wsk.y * x0;
            acc[4 * oq + 2] += wa.z * x1 + wsk.z * x0;
            acc[4 * oq + 3] += wa.w * x1 + wsk.w * x0;
        }
    }
    bool act = (tid < HH);
    #pragma unroll
    for (int o = 0; o < 64; o++) {
        float bias = m2b[layer * CH + o] + wb[layer * CH + o];
        float r = gelu_f(acc[o] + bias);
        if (act) X0[(size_t)(b * CH + o) * CS + x * XS + tid] = r;
    }
}

// ---- final head: LDS micro-GEMM (k_final3 structure, padded sV stride) ----
__global__ void __launch_bounds__(256) k_final5(const float* __restrict__ X0,
    const float* __restrict__ q1w, const float* __restrict__ q1b,
    const float* __restrict__ q2w, const float* __restrict__ q2b,
    float* __restrict__ out) {
    __shared__ float sV[CH * 132];   // 33KB, stride 132 kills 4-way conflicts
    __shared__ float sW[CH * 68];    // 17KB; sRed aliases sW
    int tid = threadIdx.x;
    int b = blockIdx.y;
    int X = blockIdx.x;
    for (int k = 0; k < 8; k++) {
        int idx = k * 256 + tid;
        int i = idx >> 5, yq = idx & 31;
        *(float4*)&sV[i * 132 + yq * 4] =
            *(const float4*)&X0[(size_t)(b * CH + i) * CS + X * XS + yq * 4];
    }
    int hg = tid & 15, yg = tid >> 4;
    int h0 = hg * 4, y0 = yg * 8;
    float qacc[8];
    #pragma unroll
    for (int c = 0; c < 8; c++) qacc[c] = 0.f;
    for (int hc = 0; hc < 4; hc++) {
        __syncthreads();
        for (int idx = tid; idx < 4096; idx += 256) {
            int h = idx >> 6, i = idx & 63;
            sW[i * 68 + h] = q1w[(hc * 64 + h) * 64 + i];
        }
        __syncthreads();
        float acc[4][8];
        #pragma unroll
        for (int a = 0; a < 4; a++)
            #pragma unroll
            for (int c = 0; c < 8; c++) acc[a][c] = 0.f;
        for (int i = 0; i < CH; i++) {
            float4 w  = *(const float4*)&sW[i * 68 + h0];
            float4 vA = *(const float4*)&sV[i * 132 + y0];
            float4 vB = *(const float4*)&sV[i * 132 + y0 + 4];
            float wv[4] = {w.x, w.y, w.z, w.w};
            float vv[8] = {vA.x, vA.y, vA.z, vA.w, vB.x, vB.y, vB.z, vB.w};
            #pragma unroll
            for (int a = 0; a < 4; a++)
                #pragma unroll
                for (int c = 0; c < 8; c++) acc[a][c] += wv[a] * vv[c];
        }
        #pragma unroll
        for (int a = 0; a < 4; a++) {
            int h = hc * 64 + h0 + a;
            float qb = q1b[h], q2v = q2w[h];
            #pragma unroll
            for (int c = 0; c < 8; c++)
                qacc[c] += q2v * gelu_f(acc[a][c] + qb);
        }
    }
    __syncthreads();
    float* sRed = sW;
    *(float4*)&sRed[hg * 132 + y0]     = make_float4(qacc[0], qacc[1], qacc[2], qacc[3]);
    *(float4*)&sRed[hg * 132 + y0 + 4] = make_float4(qacc[4], qacc[5], qacc[6], qacc[7]);
    __syncthreads();
    if (tid < 128) {
        float r = q2b[0];
        #pragma unroll
        for (int g = 0; g < 16; g++) r += sRed[g * 132 + tid];
        out[(b * SS + X) * SS + tid] = r;
    }
}

extern "C" void kernel_launch(void* const* d_in, const int* in_sizes, int n_in,
                              void* d_out, int out_size, void* d_ws, size_t ws_size,
                              hipStream_t stream) {
    const float* x   = (const float*)d_in[0];
    const float* p_w = (const float*)d_in[1];
    const float* p_b = (const float*)d_in[2];
    const float* sw1 = (const float*)d_in[3];
    const float* sw2 = (const float*)d_in[4];
    const float* m1w = (const float*)d_in[5];
    const float* m1b = (const float*)d_in[6];
    const float* m2w = (const float*)d_in[7];
    const float* m2b = (const float*)d_in[8];
    const float* wwp = (const float*)d_in[9];
    const float* wbp = (const float*)d_in[10];
    const float* q1w = (const float*)d_in[11];
    const float* q1b = (const float*)d_in[12];
    const float* q2w = (const float*)d_in[13];
    const float* q2b = (const float*)d_in[14];

    float* ws = (float*)d_ws;
    float*  X0   = ws;                                   // 20,201,472 floats
    float*  Tf   = X0 + (size_t)BB * CH * CS;            // 4,489,216 floats (T / Hh)
    float2* F    = (float2*)(Tf + (size_t)140288 * 32);  // 524,288 f2 (F / G2)
    float2* G    = F + (size_t)524288;                   // 524,288 f2
    float2* Wy   = G + (size_t)524288;                   // 2192 f2
    float2* Wx   = Wy + 2192;                            // 4384 f2
    float2* WyT  = Wx + 4384;                            // 2192 f2
    float*  wcomb = (float*)(WyT + 2192);                // 32768 floats
    float*  WS   = wcomb + 32768;                        // 4,194,304 floats (per-layer)

    k_init<<<163, 256, 0, stream>>>(Wy, Wx, WyT, wcomb, m2w, wwp);
    k_proj<<<(BB * CH * CS) / 256, 256, 0, stream>>>(x, p_w, p_b, X0);
    for (int layer = 0; layer < NL; layer++) {
        k_wtrans<<<16384, 256, 0, stream>>>(sw1, sw2, layer, WS);
        k_dfty3<<<548, 256, 0, stream>>>(X0, Wy, Tf);
        k_dftx2<<<1024, 512, 0, stream>>>(Tf, Wx, F);
        k_specmul2<<<dim3(32, 8), 256, 0, stream>>>(F, (const float2*)WS, G);
        k_mlp1m<<<dim3(16, BB), 128, 0, stream>>>((const float*)G, m1w, layer, (float*)F);
        k_invx2<<<1024, 256, 0, stream>>>(F, Wx, (float2*)Tf);
        k_fuse<<<dim3(HH, BB), 192, 0, stream>>>(X0, (const float2*)Tf, WyT, wcomb,
                                                 m1b, m2b, wbp, layer);
    }
    k_final5<<<dim3(SS, BB), 256, 0, stream>>>(X0, q1w, q1b, q2w, q2b, (float*)d_out);
}